// Round 11
// baseline (678.543 us; speedup 1.0000x reference)
//
#include <hip/hip_runtime.h>

#define SEQ   1024
#define BATCH 8192
#define HID   50
#define BT    32           // batch per block: two MFMA-N groups of 16
#define CHS   16           // steps per x chunk
#define NCH   (SEQ/CHS)
#define CHF   (CHS*BT*3)   // 1536 floats per chunk

typedef _Float16 half8 __attribute__((ext_vector_type(8)));
typedef float    f32x4 __attribute__((ext_vector_type(4)));

// state-fragment slot for value (k, batch b): layout [kh][grpk][b][i]
__device__ __forceinline__ int bslot(int k, int b){
  return (k >> 5)*512 + ((k & 31) >> 3)*128 + b*8 + (k & 7);
}

#define MFMA16(A,B,C) __builtin_amdgcn_mfma_f32_16x16x32_f16(A,B,C,0,0,0)

// chunk cg -> 3 regs; flat f = tid + 512u; step s = f/96, elem e = f%96
#define XLD(cg) {                                                          \
    const int f1 = tid + 512, f2 = tid + 1024;                             \
    const int s0_ = (tid*683) >> 16, s1_ = (f1*683) >> 16,                 \
              s2_ = (f2*683) >> 16;                                        \
    xr0 = x[(size_t)(((cg)*CHS + s0_)*BATCH + b0)*3 + (tid - 96*s0_)];     \
    xr1 = x[(size_t)(((cg)*CHS + s1_)*BATCH + b0)*3 + (f1  - 96*s1_)];     \
    xr2 = x[(size_t)(((cg)*CHS + s2_)*BATCH + b0)*3 + (f2  - 96*s2_)]; }

// r6-verbatim LSTM cell: acc[0..3] = pre-scaled (i,f,g,o); C tracks 2*log2e*c
#define ELEM(acc, C, bq, slot) {                                                       \
    const float si = __builtin_amdgcn_rcpf(1.0f + __builtin_amdgcn_exp2f((acc)[0]));   \
    const float sf = __builtin_amdgcn_rcpf(1.0f + __builtin_amdgcn_exp2f((acc)[1]));   \
    const float rg = __builtin_amdgcn_rcpf(1.0f + __builtin_amdgcn_exp2f((acc)[2]));   \
    const float so = __builtin_amdgcn_rcpf(1.0f + __builtin_amdgcn_exp2f((acc)[3]));   \
    const float G  = __builtin_fmaf(-5.77078016355584f, rg, 2.88539008177792f);        \
    C = __builtin_fmaf(sf, C, si*G);                                                   \
    const float r2 = __builtin_amdgcn_rcpf(1.0f + __builtin_amdgcn_exp2f(C));          \
    const float u_ = so * r2;                                                          \
    (bq)[slot] = (_Float16)__builtin_fmaf(-2.0f, u_, so); }

__global__ __launch_bounds__(512, 2)
void lstm_bal(const float* __restrict__ x,
              const float* __restrict__ W_ih,
              const float* __restrict__ W_hh,
              const float* __restrict__ b_ih,
              const float* __restrict__ b_hh,
              const float* __restrict__ fc_w,
              const float* __restrict__ fc_b,
              float* __restrict__ out)
{
  // two groups x double-buffered state fragment [h | x | 1 | 0-pad], MFMA-B layout
  __shared__ _Float16 Bst[2][2][1024];    // [group][buf]  (8 KB)
  __shared__ float    xb[2][CHF];         // x chunk double buffer (12 KB)
  // + 64 KB dynamic LDS at launch -> 1 block/CU guaranteed (no 2-on-1 packing)

  const int tid  = threadIdx.x;
  const int w    = tid >> 6;              // 0..7
  const int lane = tid & 63;
  const int r16  = lane & 15;             // batch col
  const int grp  = lane >> 4;
  const int b0   = blockIdx.x * BT;
  const float L2E = 1.44269504088896f;

  // ---- balanced tile-unit map: 24 full units (tiles 0..11 x {A,B}) = 3/wave,
  // two half units (tile 12: grp<2 only) on waves 2 (A) and 7 (B).
  // wave w: U0=(A,w), U1=(B,w), U2=(w<4 ? (A,8+w) : (B,4+w)), U3=half.
  const int  t1   = w;
  const bool exA  = (w < 4);              // extra unit's group
  const int  tE   = exA ? (8 + w) : (4 + w);
  const bool hasH = (w == 2) || (w == 7); // wave-uniform!
  const bool hA   = (w == 2);             // half unit's group

  // ---- weight fragments for tiles {t1, tE, 12}; rows permuted c=4j+gate,
  // pre-scaled: gates i,f,o by -log2e (sigmoid), g by +2log2e (tanh)
  const int tiles[3] = {t1, tE, 12};
  half8 Af[3][2];
  #pragma unroll
  for (int it = 0; it < 3; ++it) {
    const int tile = tiles[it];
    #pragma unroll
    for (int kh = 0; kh < 2; ++kh) {
      half8 f;
      #pragma unroll
      for (int i = 0; i < 8; ++i) {
        const int k = kh*32 + grp*8 + i;
        const int c = tile*16 + r16;
        float wv = 0.0f;
        if (c < 4*HID) {
          const int j = c >> 2, gi = c & 3;
          const int go = gi*HID + j;                     // i,f,g,o row order
          const float sc = (gi == 2) ? (2.0f*L2E) : (-L2E);
          if (k < HID)      wv = W_hh[go*HID + k] * sc;
          else if (k < 53)  wv = W_ih[go*3 + (k-50)] * sc;
          else if (k == 53) wv = (b_ih[go] + b_hh[go]) * sc;
        }
        f[i] = (_Float16)wv;
      }
      Af[it][kh] = f;
    }
  }

  // h-write slots: item (b=r16, j=tile*4+grp)
  const int ws1 = bslot(t1*4 + grp, r16);          // j <= 31
  const int wsE = bslot(tE*4 + grp, r16);          // j <= 47
  const int wsH = bslot((48 + grp < HID) ? 48 + grp : 0, r16);

  // ---- init: zero all state buffers; then bias "1.0" slots (k=53) ----
  #pragma unroll
  for (int i = 0; i < 4; ++i) ((unsigned*)Bst)[tid + 512*i] = 0u;
  __syncthreads();
  if (tid < 64) Bst[tid >> 5][(tid >> 4) & 1][768 + (tid & 15)*8 + 5] = (_Float16)1.0f;

  // ---- x prologue: chunks 0,1 -> LDS; chunk 2 -> regs ----
  float xr0, xr1, xr2;
  XLD(0); xb[0][tid] = xr0; xb[0][tid+512] = xr1; xb[0][tid+1024] = xr2;
  XLD(1); xb[1][tid] = xr0; xb[1][tid+512] = xr1; xb[1][tid+1024] = xr2;
  XLD(2);
  __syncthreads();
  if (tid < 96) {                         // x for step 0 into both groups
    const int g = tid >= 48, l = tid - 48*g;
    const int bb = (l*171) >> 9, e = l - 3*bb;
    Bst[g][0][768 + bb*8 + 2 + e] = (_Float16)xb[0][tid];
  }
  __syncthreads();

  float cs1A = 0.f, cs1B = 0.f, csE = 0.f, csH = 0.f;

  auto step = [&](int t, int p, int q) {
    _Float16* bqA = &Bst[0][q][0];
    _Float16* bqB = &Bst[1][q][0];
    // both groups' state fragments (B operand): col b=r16, k=grp*8+i (+32)
    const half8 sA0 = *(const half8*)&Bst[0][p][lane*8];
    const half8 sA1 = *(const half8*)&Bst[0][p][512 + lane*8];
    const half8 sB0 = *(const half8*)&Bst[1][p][lane*8];
    const half8 sB1 = *(const half8*)&Bst[1][p][512 + lane*8];
    f32x4 aA = {0.f,0.f,0.f,0.f}, aB = {0.f,0.f,0.f,0.f};
    aA = MFMA16(Af[0][0], sA0, aA);  aA = MFMA16(Af[0][1], sA1, aA);
    aB = MFMA16(Af[0][0], sB0, aB);  aB = MFMA16(Af[0][1], sB1, aB);
    f32x4 aE = {0.f,0.f,0.f,0.f};
    aE = MFMA16(Af[1][0], exA ? sA0 : sB0, aE);
    aE = MFMA16(Af[1][1], exA ? sA1 : sB1, aE);
    if (hasH) {                          // wave-uniform: full-exec MFMA
      f32x4 aH = {0.f,0.f,0.f,0.f};
      aH = MFMA16(Af[2][0], hA ? sA0 : sB0, aH);
      aH = MFMA16(Af[2][1], hA ? sA1 : sB1, aH);
      if (grp < 2) ELEM(aH, csH, (hA ? bqA : bqB), wsH);   // lane-gated ELEM only
    }
    ELEM(aE, csE, (exA ? bqA : bqB), wsE);
    ELEM(aA, cs1A, bqA, ws1);
    ELEM(aB, cs1B, bqB, ws1);
    // x(t+1) staging on 3-unit waves 1 (SIMD1, group A) and 4 (SIMD0, group B)
    if ((w == 1 || w == 4) && lane < 48) {
      const int tn = t + 1;
      const int bb = (lane*171) >> 9, e = lane - 3*bb;
      const float xv = xb[(tn >> 4) & 1][(tn & 15)*96 + (w == 4 ? 48 : 0) + lane];
      (w == 1 ? bqA : bqB)[768 + bb*8 + 2 + e] = (_Float16)xv;
    }
    // LDS-only barrier: do NOT drain vmcnt (x prefetch stays in flight)
    asm volatile("s_waitcnt lgkmcnt(0)\n\ts_barrier" ::: "memory");
  };

  #pragma unroll 1
  for (int tc = 0; tc < NCH; ++tc) {
    if (tc > 0) {
      const int pc = (tc + 1) & 1;        // commit chunk tc+1 (issued at tc-1)
      xb[pc][tid] = xr0; xb[pc][tid+512] = xr1; xb[pc][tid+1024] = xr2;
      if (tc + 2 < NCH) { XLD(tc+2); }
    }
    const int tb = tc*CHS;
    #pragma unroll 1
    for (int u = 0; u < CHS/2; ++u) {
      step(tb + 2*u,     0, 1);
      step(tb + 2*u + 1, 1, 0);
    }
  }

  // ---- epilogue: h_1024 sits in buf 0 of each group ----
  __syncthreads();
  if (tid < BT) {
    const int g = tid >> 4, b = tid & 15;
    float s = fc_b[0];
    #pragma unroll
    for (int j = 0; j < HID; ++j)
      s += fc_w[j] * (float)Bst[g][0][bslot(j, b)];
    out[b0 + tid] = s;
  }
}

extern "C" void kernel_launch(void* const* d_in, const int* in_sizes, int n_in,
                              void* d_out, int out_size, void* d_ws, size_t ws_size,
                              hipStream_t stream)
{
  const float* x    = (const float*)d_in[0];
  const float* W_ih = (const float*)d_in[1];
  const float* W_hh = (const float*)d_in[2];
  const float* b_ih = (const float*)d_in[3];
  const float* b_hh = (const float*)d_in[4];
  const float* fc_w = (const float*)d_in[5];
  const float* fc_b = (const float*)d_in[6];
  // 64 KB dynamic LDS (unused) -> ~84 KB/block -> exactly 1 block/CU
  lstm_bal<<<BATCH/BT, 512, 65536, stream>>>(x, W_ih, W_hh, b_ih, b_hh,
                                             fc_w, fc_b, (float*)d_out);
}

// Round 12
// 604.750 us; speedup vs baseline: 1.1220x; 1.1220x over previous
//
#include <hip/hip_runtime.h>

#define SEQ   1024
#define BATCH 8192
#define HID   50
#define BT    32           // batch per block: two MFMA-N groups of 16
#define CHS   16           // steps per x chunk
#define NCH   (SEQ/CHS)
#define CHF   (CHS*BT*3)   // 1536 floats per chunk

typedef _Float16 half8 __attribute__((ext_vector_type(8)));
typedef float    f32x4 __attribute__((ext_vector_type(4)));

// state-fragment slot for value (k, batch b): layout [kh][grpk][b][i]
__device__ __forceinline__ int bslot(int k, int b){
  return (k >> 5)*512 + ((k & 31) >> 3)*128 + b*8 + (k & 7);
}

#define MFMA16(A,B,C) __builtin_amdgcn_mfma_f32_16x16x32_f16(A,B,C,0,0,0)

// chunk cg -> 3 regs; flat f = tid + 512u; step s = f/96, elem e = f%96
#define XLD(cg) {                                                          \
    const int f1 = tid + 512, f2 = tid + 1024;                             \
    const int s0_ = (tid*683) >> 16, s1_ = (f1*683) >> 16,                 \
              s2_ = (f2*683) >> 16;                                        \
    xr0 = x[(size_t)(((cg)*CHS + s0_)*BATCH + b0)*3 + (tid - 96*s0_)];     \
    xr1 = x[(size_t)(((cg)*CHS + s1_)*BATCH + b0)*3 + (f1  - 96*s1_)];     \
    xr2 = x[(size_t)(((cg)*CHS + s2_)*BATCH + b0)*3 + (f2  - 96*s2_)]; }

// r6-verbatim LSTM cell: acc[0..3] = pre-scaled (i,f,g,o); C tracks 2*log2e*c
#define ELEM(acc, C, bq, slot) {                                                       \
    const float si = __builtin_amdgcn_rcpf(1.0f + __builtin_amdgcn_exp2f((acc)[0]));   \
    const float sf = __builtin_amdgcn_rcpf(1.0f + __builtin_amdgcn_exp2f((acc)[1]));   \
    const float rg = __builtin_amdgcn_rcpf(1.0f + __builtin_amdgcn_exp2f((acc)[2]));   \
    const float so = __builtin_amdgcn_rcpf(1.0f + __builtin_amdgcn_exp2f((acc)[3]));   \
    const float G  = __builtin_fmaf(-5.77078016355584f, rg, 2.88539008177792f);        \
    C = __builtin_fmaf(sf, C, si*G);                                                   \
    const float r2 = __builtin_amdgcn_rcpf(1.0f + __builtin_amdgcn_exp2f(C));          \
    const float u_ = so * r2;                                                          \
    (bq)[slot] = (_Float16)__builtin_fmaf(-2.0f, u_, so); }

__global__ __launch_bounds__(512, 2)
void lstm_gp(const float* __restrict__ x,
             const float* __restrict__ W_ih,
             const float* __restrict__ W_hh,
             const float* __restrict__ b_ih,
             const float* __restrict__ b_hh,
             const float* __restrict__ fc_w,
             const float* __restrict__ fc_b,
             float* __restrict__ out)
{
  // two groups x double-buffered state fragment [h | x | 1 | 0-pad], MFMA-B layout
  __shared__ _Float16 Bst[2][2][1024];    // [group][buf]  (8 KB)
  __shared__ float    xb[2][CHF];         // x chunk double buffer (12 KB)
  // + 64 KB dynamic LDS at launch -> 1 block/CU guaranteed (no 2-on-1 packing)

  const int tid  = threadIdx.x;
  const int w    = tid >> 6;              // 0..7
  const int lane = tid & 63;
  const int r16  = lane & 15;             // batch col
  const int grp  = lane >> 4;
  const int b0   = blockIdx.x * BT;
  const float L2E = 1.44269504088896f;

  // ---- group-pure tile map: waves 0..3 -> group A, waves 4..7 -> group B.
  // base tile tA = w (A) / 7-w (B); each wave: tiles {tA, tA+4, tA+8};
  // half-tile 12 (j=48,49) on w0 (A) and w7 (B).  Per-SIMD ELEM load:
  // {3.5+3, 3+3, 3+3, 3+3.5} = {6.5, 6, 6, 6.5}.
  const int  g    = (w < 4) ? 0 : 1;
  const int  tA   = (w < 4) ? w : (7 - w);
  const bool hasH = (w == 0) || (w == 7); // wave-uniform (MFMA-safe, r10 lesson)

  // ---- weight fragments for tiles {tA, tA+4, tA+8, 12}; rows permuted
  // c=4j+gate, pre-scaled: i,f,o by -log2e (sigmoid), g by +2log2e (tanh)
  const int tiles[4] = {tA, tA + 4, tA + 8, 12};
  half8 Af[4][2];
  #pragma unroll
  for (int it = 0; it < 4; ++it) {
    const int tile = tiles[it];
    #pragma unroll
    for (int kh = 0; kh < 2; ++kh) {
      half8 f;
      #pragma unroll
      for (int i = 0; i < 8; ++i) {
        const int k = kh*32 + grp*8 + i;
        const int c = tile*16 + r16;
        float wv = 0.0f;
        if (c < 4*HID) {
          const int j = c >> 2, gi = c & 3;
          const int go = gi*HID + j;                     // i,f,g,o row order
          const float sc = (gi == 2) ? (2.0f*L2E) : (-L2E);
          if (k < HID)      wv = W_hh[go*HID + k] * sc;
          else if (k < 53)  wv = W_ih[go*3 + (k-50)] * sc;
          else if (k == 53) wv = (b_ih[go] + b_hh[go]) * sc;
        }
        f[i] = (_Float16)wv;
      }
      Af[it][kh] = f;
    }
  }

  // h-write slots: item (b=r16, j=tile*4+grp); tile 12 valid only for grp<2
  int ws[4];
  #pragma unroll
  for (int it = 0; it < 4; ++it) {
    const int j = tiles[it]*4 + grp;
    ws[it] = bslot((j < HID) ? j : 0, r16);
  }

  // ---- init: zero all state buffers; then bias "1.0" slots (k=53) ----
  #pragma unroll
  for (int i = 0; i < 4; ++i) ((unsigned*)Bst)[tid + 512*i] = 0u;
  __syncthreads();
  if (tid < 64) Bst[tid >> 5][(tid >> 4) & 1][768 + (tid & 15)*8 + 5] = (_Float16)1.0f;

  // ---- x prologue: chunks 0,1 -> LDS; chunk 2 -> regs ----
  float xr0, xr1, xr2;
  XLD(0); xb[0][tid] = xr0; xb[0][tid+512] = xr1; xb[0][tid+1024] = xr2;
  XLD(1); xb[1][tid] = xr0; xb[1][tid+512] = xr1; xb[1][tid+1024] = xr2;
  XLD(2);
  __syncthreads();
  if (tid < 96) {                         // x for step 0 into both groups
    const int gg = tid >= 48, l = tid - 48*gg;
    const int bb = (l*171) >> 9, e = l - 3*bb;
    Bst[gg][0][768 + bb*8 + 2 + e] = (_Float16)xb[0][tid];
  }
  __syncthreads();

  float cs[4] = {0.f, 0.f, 0.f, 0.f};

  auto step = [&](int t, int p, int q) {
    _Float16* bq = &Bst[g][q][0];
    // OWN group's state fragment only: 2 ds_read_b128 (was 4)
    const half8 s0 = *(const half8*)&Bst[g][p][lane*8];
    const half8 s1 = *(const half8*)&Bst[g][p][512 + lane*8];
    f32x4 a0 = {0.f,0.f,0.f,0.f}, a1 = a0, a2 = a0;
    a0 = MFMA16(Af[0][0], s0, a0);  a0 = MFMA16(Af[0][1], s1, a0);
    a1 = MFMA16(Af[1][0], s0, a1);  a1 = MFMA16(Af[1][1], s1, a1);
    a2 = MFMA16(Af[2][0], s0, a2);  a2 = MFMA16(Af[2][1], s1, a2);
    if (hasH) {                          // wave-uniform: full-exec MFMA
      f32x4 a3 = {0.f,0.f,0.f,0.f};
      a3 = MFMA16(Af[3][0], s0, a3);  a3 = MFMA16(Af[3][1], s1, a3);
      if (grp < 2) ELEM(a3, cs[3], bq, ws[3]);   // lane-gated ELEM only
    }
    ELEM(a0, cs[0], bq, ws[0]);
    ELEM(a1, cs[1], bq, ws[1]);
    ELEM(a2, cs[2], bq, ws[2]);
    // x(t+1) staging on the 3-unit waves 1 (group A) and 6 (group B)
    if ((w == 1 || w == 6) && lane < 48) {
      const int tn = t + 1;
      const int bb = (lane*171) >> 9, e = lane - 3*bb;
      const float xv = xb[(tn >> 4) & 1][(tn & 15)*96 + (w == 6 ? 48 : 0) + lane];
      bq[768 + bb*8 + 2 + e] = (_Float16)xv;
    }
    // LDS-only barrier: do NOT drain vmcnt (x prefetch stays in flight)
    asm volatile("s_waitcnt lgkmcnt(0)\n\ts_barrier" ::: "memory");
  };

  #pragma unroll 1
  for (int tc = 0; tc < NCH; ++tc) {
    if (tc > 0) {
      const int pc = (tc + 1) & 1;        // commit chunk tc+1 (issued at tc-1)
      xb[pc][tid] = xr0; xb[pc][tid+512] = xr1; xb[pc][tid+1024] = xr2;
      if (tc + 2 < NCH) { XLD(tc+2); }
    }
    const int tb = tc*CHS;
    #pragma unroll 1
    for (int u = 0; u < CHS/2; ++u) {
      step(tb + 2*u,     0, 1);
      step(tb + 2*u + 1, 1, 0);
    }
  }

  // ---- epilogue: h_1024 sits in buf 0 of each group ----
  __syncthreads();
  if (tid < BT) {
    const int gg = tid >> 4, b = tid & 15;
    float s = fc_b[0];
    #pragma unroll
    for (int j = 0; j < HID; ++j)
      s += fc_w[j] * (float)Bst[gg][0][bslot(j, b)];
    out[b0 + tid] = s;
  }
}

extern "C" void kernel_launch(void* const* d_in, const int* in_sizes, int n_in,
                              void* d_out, int out_size, void* d_ws, size_t ws_size,
                              hipStream_t stream)
{
  const float* x    = (const float*)d_in[0];
  const float* W_ih = (const float*)d_in[1];
  const float* W_hh = (const float*)d_in[2];
  const float* b_ih = (const float*)d_in[3];
  const float* b_hh = (const float*)d_in[4];
  const float* fc_w = (const float*)d_in[5];
  const float* fc_b = (const float*)d_in[6];
  // 64 KB dynamic LDS (unused) -> ~84 KB/block -> exactly 1 block/CU
  lstm_gp<<<BATCH/BT, 512, 65536, stream>>>(x, W_ih, W_hh, b_ih, b_hh,
                                            fc_w, fc_b, (float*)d_out);
}

// Round 13
// 541.872 us; speedup vs baseline: 1.2522x; 1.1160x over previous
//
#include <hip/hip_runtime.h>

#define SEQ   1024
#define BATCH 8192
#define HID   50
#define BT    32           // batch per block: two MFMA-N groups of 16
#define CHS   16           // steps per x chunk
#define NCH   (SEQ/CHS)
#define CHF   (CHS*BT*3)   // 1536 floats per chunk

typedef _Float16 half8 __attribute__((ext_vector_type(8)));
typedef float    f32x4 __attribute__((ext_vector_type(4)));

// state-fragment slot for value (k, batch b): layout [kh][grpk][b][i]
__device__ __forceinline__ int bslot(int k, int b){
  return (k >> 5)*512 + ((k & 31) >> 3)*128 + b*8 + (k & 7);
}

#define MFMA16(A,B,C) __builtin_amdgcn_mfma_f32_16x16x32_f16(A,B,C,0,0,0)

// chunk cg -> 3 regs; flat f = tid + 512u; step s = f/96, elem e = f%96
#define XLD(cg) {                                                          \
    const int f1 = tid + 512, f2 = tid + 1024;                             \
    const int s0_ = (tid*683) >> 16, s1_ = (f1*683) >> 16,                 \
              s2_ = (f2*683) >> 16;                                        \
    xr0 = x[(size_t)(((cg)*CHS + s0_)*BATCH + b0)*3 + (tid - 96*s0_)];     \
    xr1 = x[(size_t)(((cg)*CHS + s1_)*BATCH + b0)*3 + (f1  - 96*s1_)];     \
    xr2 = x[(size_t)(((cg)*CHS + s2_)*BATCH + b0)*3 + (f2  - 96*s2_)]; }

// all 4 gates of one item in acc[0..3] (pre-scaled); C tracks 2*log2e*c
#define ELEM(acc, C, bq, slot) {                                                       \
    const float si = __builtin_amdgcn_rcpf(1.0f + __builtin_amdgcn_exp2f((acc)[0]));   \
    const float sf = __builtin_amdgcn_rcpf(1.0f + __builtin_amdgcn_exp2f((acc)[1]));   \
    const float rg = __builtin_amdgcn_rcpf(1.0f + __builtin_amdgcn_exp2f((acc)[2]));   \
    const float so = __builtin_amdgcn_rcpf(1.0f + __builtin_amdgcn_exp2f((acc)[3]));   \
    const float G  = __builtin_fmaf(-5.77078016355584f, rg, 2.88539008177792f);        \
    C = __builtin_fmaf(sf, C, si*G);                                                   \
    const float r2 = __builtin_amdgcn_rcpf(1.0f + __builtin_amdgcn_exp2f(C));          \
    const float u_ = so * r2;                                                          \
    (bq)[slot] = (_Float16)__builtin_fmaf(-2.0f, u_, so); }

__global__ __launch_bounds__(512, 2)
void lstm_g2(const float* __restrict__ x,
             const float* __restrict__ W_ih,
             const float* __restrict__ W_hh,
             const float* __restrict__ b_ih,
             const float* __restrict__ b_hh,
             const float* __restrict__ fc_w,
             const float* __restrict__ fc_b,
             float* __restrict__ out)
{
  // two groups x double-buffered state fragment [h | x | 1 | 0-pad], MFMA-B layout
  __shared__ _Float16 Bst[2][2][1024];    // [group][buf]  (8 KB)
  __shared__ float    xb[2][CHF];         // x chunk double buffer (12 KB)
  // + 64 KB dynamic LDS at launch -> 84 KB total -> hardware-capped 1 block/CU

  const int tid  = threadIdx.x;
  const int w    = tid >> 6;              // 0..7
  const int lane = tid & 63;
  const int r16  = lane & 15;             // batch col
  const int grp  = lane >> 4;
  const int b0   = blockIdx.x * BT;
  const float L2E = 1.44269504088896f;

  // ---- tile-unit assignment: 26 units (13 tiles x {A,B}) over 8 waves ----
  // every wave: (A,t1),(B,t1) with t1=w.  extras:
  //   w0,w1: (A,8+w),(B,8+w);  w2..w4: (A,8+w);  w5..w7: (B,5+w)
  const int  t1    = w;
  const int  t2    = (w < 5) ? (8 + w) : (5 + w);
  const bool hasA2 = (w < 5);
  const bool hasB2 = (w < 2) || (w >= 5);

  // ---- A fragments (weights) for tiles t1,t2; rows permuted c=4j+gate, pre-scaled:
  // gates i,f,o by -log2e (sigmoid via exp2), g by +2log2e (tanh via exp2)
  half8 Af[2][2];
  #pragma unroll
  for (int it = 0; it < 2; ++it) {
    const int tile = it ? t2 : t1;
    #pragma unroll
    for (int kh = 0; kh < 2; ++kh) {
      half8 f;
      #pragma unroll
      for (int i = 0; i < 8; ++i) {
        const int k = kh*32 + grp*8 + i;
        const int c = tile*16 + r16;
        float wv = 0.0f;
        if (c < 4*HID) {
          const int j = c >> 2, gi = c & 3;
          const int go = gi*HID + j;                     // i,f,g,o row order
          const float sc = (gi == 2) ? (2.0f*L2E) : (-L2E);
          if (k < HID)      wv = W_hh[go*HID + k] * sc;
          else if (k < 53)  wv = W_ih[go*3 + (k-50)] * sc;
          else if (k == 53) wv = (b_ih[go] + b_hh[go]) * sc;
        }
        f[i] = (_Float16)wv;
      }
      Af[it][kh] = f;
    }
  }

  // h-write slots: unit (tile): item (b=r16, j=tile*4+grp), 4 gates in acc[0..3]
  const int j2  = t2*4 + grp;
  const int ws1 = bslot(t1*4 + grp, r16);
  const int ws2 = bslot((j2 < HID) ? j2 : 0, r16);
  const bool m2 = (j2 < HID);             // only t2==12, grp>=2 is invalid

  // ---- init: zero all state buffers; then bias "1.0" slots (k=53) ----
  #pragma unroll
  for (int i = 0; i < 4; ++i) ((unsigned*)Bst)[tid + 512*i] = 0u;
  __syncthreads();
  if (tid < 64) Bst[tid >> 5][(tid >> 4) & 1][768 + (tid & 15)*8 + 5] = (_Float16)1.0f;

  // ---- x prologue: chunks 0,1 -> LDS; chunk 2 -> regs ----
  float xr0, xr1, xr2;
  XLD(0); xb[0][tid] = xr0; xb[0][tid+512] = xr1; xb[0][tid+1024] = xr2;
  XLD(1); xb[1][tid] = xr0; xb[1][tid+512] = xr1; xb[1][tid+1024] = xr2;
  XLD(2);
  __syncthreads();
  if (tid < 96) {                         // x for step 0 into both groups
    const int g = tid >= 48, l = tid - 48*g;
    const int bb = (l*171) >> 9, e = l - 3*bb;
    Bst[g][0][768 + bb*8 + 2 + e] = (_Float16)xb[0][tid];
  }
  __syncthreads();

  float csA0 = 0.f, csA1 = 0.f, csB0 = 0.f, csB1 = 0.f;

  auto step = [&](int t, int p, int q) {
    _Float16* bqA = &Bst[0][q][0];
    _Float16* bqB = &Bst[1][q][0];
    // both groups' state fragments (B operand): col b=r16, k=grp*8+i (+32)
    const half8 sA0 = *(const half8*)&Bst[0][p][lane*8];
    const half8 sA1 = *(const half8*)&Bst[0][p][512 + lane*8];
    const half8 sB0 = *(const half8*)&Bst[1][p][lane*8];
    const half8 sB1 = *(const half8*)&Bst[1][p][512 + lane*8];
    f32x4 aA0 = {0.f,0.f,0.f,0.f}, aB0 = {0.f,0.f,0.f,0.f};
    aA0 = MFMA16(Af[0][0], sA0, aA0);  aA0 = MFMA16(Af[0][1], sA1, aA0);
    aB0 = MFMA16(Af[0][0], sB0, aB0);  aB0 = MFMA16(Af[0][1], sB1, aB0);
    if (hasA2) {
      f32x4 aA1 = {0.f,0.f,0.f,0.f};
      aA1 = MFMA16(Af[1][0], sA0, aA1);  aA1 = MFMA16(Af[1][1], sA1, aA1);
      if (m2) ELEM(aA1, csA1, bqA, ws2);
    }
    if (hasB2) {
      f32x4 aB1 = {0.f,0.f,0.f,0.f};
      aB1 = MFMA16(Af[1][0], sB0, aB1);  aB1 = MFMA16(Af[1][1], sB1, aB1);
      if (m2) ELEM(aB1, csB1, bqB, ws2);
    }
    ELEM(aA0, csA0, bqA, ws1);
    ELEM(aB0, csB0, bqB, ws1);
    // x for step t+1 into the write buffers (waves 2,3: lighter load)
    if ((w == 2 || w == 3) && lane < 48) {
      const int tn = t + 1;
      const int bb = (lane*171) >> 9, e = lane - 3*bb;
      const float xv = xb[(tn >> 4) & 1][(tn & 15)*96 + (w - 2)*48 + lane];
      (w == 2 ? bqA : bqB)[768 + bb*8 + 2 + e] = (_Float16)xv;
    }
    // LDS-only barrier: do NOT drain vmcnt (x prefetch stays in flight)
    asm volatile("s_waitcnt lgkmcnt(0)\n\ts_barrier" ::: "memory");
  };

  #pragma unroll 1
  for (int tc = 0; tc < NCH; ++tc) {
    if (tc > 0) {
      const int pc = (tc + 1) & 1;        // commit chunk tc+1 (issued at tc-1)
      xb[pc][tid] = xr0; xb[pc][tid+512] = xr1; xb[pc][tid+1024] = xr2;
      if (tc + 2 < NCH) { XLD(tc+2); }
    }
    const int tb = tc*CHS;
    #pragma unroll 1
    for (int u = 0; u < CHS/2; ++u) {
      step(tb + 2*u,     0, 1);
      step(tb + 2*u + 1, 1, 0);
    }
  }

  // ---- epilogue: h_1024 sits in buf 0 of each group ----
  __syncthreads();
  if (tid < BT) {
    const int g = tid >> 4, b = tid & 15;
    float s = fc_b[0];
    #pragma unroll
    for (int j = 0; j < HID; ++j)
      s += fc_w[j] * (float)Bst[g][0][bslot(j, b)];
    out[b0 + tid] = s;
  }
}

extern "C" void kernel_launch(void* const* d_in, const int* in_sizes, int n_in,
                              void* d_out, int out_size, void* d_ws, size_t ws_size,
                              hipStream_t stream)
{
  const float* x    = (const float*)d_in[0];
  const float* W_ih = (const float*)d_in[1];
  const float* W_hh = (const float*)d_in[2];
  const float* b_ih = (const float*)d_in[3];
  const float* b_hh = (const float*)d_in[4];
  const float* fc_w = (const float*)d_in[5];
  const float* fc_b = (const float*)d_in[6];
  // 64 KB dynamic LDS (unused) pushes block LDS to ~84 KB -> exactly 1 block/CU
  lstm_g2<<<BATCH/BT, 512, 65536, stream>>>(x, W_ih, W_hh, b_ih, b_hh, fc_w, fc_b,
                                            (float*)d_out);
}